// Round 2
// baseline (1021.780 us; speedup 1.0000x reference)
//
#include <hip/hip_runtime.h>

typedef __attribute__((ext_vector_type(8))) short s16x8;
typedef __attribute__((ext_vector_type(4))) float f32x4;
typedef unsigned short u16;

__device__ __forceinline__ float bu2f(u16 u) {
    union { unsigned int i; float f; } x; x.i = ((unsigned int)u) << 16; return x.f;
}
__device__ __forceinline__ u16 f2bu(float f) {
    union { float f; unsigned int i; } x; x.f = f;
    unsigned int r = x.i + 0x7fffu + ((x.i >> 16) & 1u);   // RNE
    return (u16)(r >> 16);
}

__device__ __forceinline__ void gld_lds16(const void* g, void* l) {
    __builtin_amdgcn_global_load_lds(
        (const __attribute__((address_space(1))) unsigned int*)g,
        (__attribute__((address_space(3))) unsigned int*)l, 16, 0, 0);
}
#define WAIT_VM0()   asm volatile("s_waitcnt vmcnt(0)" ::: "memory")
#define WAIT_LGKM0() asm volatile("s_waitcnt lgkmcnt(0)" ::: "memory")
#define MEMBAR()     asm volatile("" ::: "memory")

// ---------------------------------------------------------------- transpose + f32->bf16
// src f32 (R,C) -> dst bf16 (C,R), 32x32 tiles
__global__ __launch_bounds__(256)
void transpose_k(const float* __restrict__ src, u16* __restrict__ dst, int R, int C) {
    __shared__ u16 t[32][33];
    int bx = blockIdx.x * 32, by = blockIdx.y * 32;
    int x = bx + threadIdx.x;
#pragma unroll
    for (int k = 0; k < 4; ++k)
        t[threadIdx.y + k * 8][threadIdx.x] = f2bu(src[(size_t)(by + threadIdx.y + k * 8) * C + x]);
    __syncthreads();
    int x2 = by + threadIdx.x;
#pragma unroll
    for (int k = 0; k < 4; ++k)
        dst[(size_t)(bx + threadIdx.y + k * 8) * R + x2] = t[threadIdx.x][threadIdx.y + k * 8];
}

// ---------------------------------------------------------------- f32 -> bf16 convert
__global__ __launch_bounds__(256)
void convert_k(const float* __restrict__ a, u16* __restrict__ o, int n4) {
    int i = blockIdx.x * 256 + threadIdx.x;
    if (i >= n4) return;
    float4 v = ((const float4*)a)[i];
    ushort4 u;
    u.x = f2bu(v.x); u.y = f2bu(v.y); u.z = f2bu(v.z); u.w = f2bu(v.w);
    ((ushort4*)o)[i] = u;
}

// ---------------------------------------------------------------- rmsnorm (row = 1024), f32 in -> bf16 out
__global__ __launch_bounds__(256)
void rmsnorm_k(const float* __restrict__ x, const float* __restrict__ g, u16* __restrict__ y) {
    const int row = blockIdx.x, tid = threadIdx.x;
    float4 v = ((const float4*)(x + (size_t)row * 1024))[tid];
    float ss = v.x * v.x + v.y * v.y + v.z * v.z + v.w * v.w;
#pragma unroll
    for (int off = 32; off; off >>= 1) ss += __shfl_xor(ss, off, 64);
    __shared__ float red[4];
    if ((tid & 63) == 0) red[tid >> 6] = ss;
    __syncthreads();
    float tot = red[0] + red[1] + red[2] + red[3];
    float sc = rsqrtf(tot * (1.f / 1024.f) + 1e-6f);
    float4 gv = ((const float4*)g)[tid];
    ushort4 o;
    o.x = f2bu(v.x * sc * gv.x);
    o.y = f2bu(v.y * sc * gv.y);
    o.z = f2bu(v.z * sc * gv.z);
    o.w = f2bu(v.w * sc * gv.w);
    ((ushort4*)(y + (size_t)row * 1024))[tid] = o;
}

// ---------------------------------------------------------------- silu(a)*b  (bf16)
__global__ __launch_bounds__(256)
void silumul_k(const u16* __restrict__ a, const u16* __restrict__ b, u16* __restrict__ o, int n4) {
    int i = blockIdx.x * 256 + threadIdx.x;
    if (i >= n4) return;
    ushort4 ua = ((const ushort4*)a)[i], ub = ((const ushort4*)b)[i];
    ushort4 uo;
    {
        float v = bu2f(ua.x); uo.x = f2bu(v / (1.f + __expf(-v)) * bu2f(ub.x));
        v = bu2f(ua.y); uo.y = f2bu(v / (1.f + __expf(-v)) * bu2f(ub.y));
        v = bu2f(ua.z); uo.z = f2bu(v / (1.f + __expf(-v)) * bu2f(ub.z));
        v = bu2f(ua.w); uo.w = f2bu(v / (1.f + __expf(-v)) * bu2f(ub.w));
    }
    ((ushort4*)o)[i] = uo;
}

// ---------------------------------------------------------------- GEMM  C(M,N) = A(M,K) @ Bt(N,K)^T
// A,Bt bf16. modes:
//  0: bf16 C = acc
//  1: bf16 C = acc + bf16 res
//  2: f32  C = 2*acc
//  3: bf16 V-transpose write C[((b*16+h)*64+d)*1024 + s]
//  4: f32  C = acc + f32 res
__global__ __launch_bounds__(256, 2)
void gemm_bt(const u16* __restrict__ A, const u16* __restrict__ Bt, void* __restrict__ C,
             const void* __restrict__ res, int M, int N, int K, int mode) {
    __shared__ u16 sA[128 * 32];
    __shared__ u16 sB[128 * 32];
    const int tid = threadIdx.x;
    const int w = tid >> 6, lane = tid & 63, q4 = lane >> 4, l16 = lane & 15;
    const int m0 = blockIdx.y * 128, n0 = blockIdx.x * 128;
    const int wm = (w >> 1) * 64, wn = (w & 1) * 64;

    const f32x4 fzero = {0.f, 0.f, 0.f, 0.f};
    f32x4 acc[4][4];
#pragma unroll
    for (int i = 0; i < 4; ++i)
#pragma unroll
        for (int j = 0; j < 4; ++j) acc[i][j] = fzero;

    const int r0 = tid >> 2, c0 = (tid & 3) * 8;  // 16B chunk per thread

    for (int k0 = 0; k0 < K; k0 += 32) {
        gld_lds16(A + (size_t)(m0 + r0) * K + k0 + c0, &sA[tid * 8]);
        gld_lds16(A + (size_t)(m0 + 64 + r0) * K + k0 + c0, &sA[(256 + tid) * 8]);
        gld_lds16(Bt + (size_t)(n0 + r0) * K + k0 + c0, &sB[tid * 8]);
        gld_lds16(Bt + (size_t)(n0 + 64 + r0) * K + k0 + c0, &sB[(256 + tid) * 8]);
        WAIT_VM0();
        __syncthreads();
        s16x8 af[4], bfr[4];
#pragma unroll
        for (int i = 0; i < 4; ++i) af[i] = *(const s16x8*)&sA[(wm + i * 16 + l16) * 32 + q4 * 8];
#pragma unroll
        for (int j = 0; j < 4; ++j) bfr[j] = *(const s16x8*)&sB[(wn + j * 16 + l16) * 32 + q4 * 8];
#pragma unroll
        for (int i = 0; i < 4; ++i)
#pragma unroll
            for (int j = 0; j < 4; ++j)
                acc[i][j] = __builtin_amdgcn_mfma_f32_16x16x32_bf16(af[i], bfr[j], acc[i][j], 0, 0, 0);
        __syncthreads();
    }

#pragma unroll
    for (int i = 0; i < 4; ++i)
#pragma unroll
        for (int j = 0; j < 4; ++j)
#pragma unroll
            for (int r = 0; r < 4; ++r) {
                int m = m0 + wm + i * 16 + q4 * 4 + r;
                int n = n0 + wn + j * 16 + l16;
                float v = acc[i][j][r];
                if (mode == 3) {
                    int b = m >> 10, s = m & 1023, hh = n >> 6, d = n & 63;
                    ((u16*)C)[(size_t)((b * 16 + hh) * 64 + d) * 1024 + s] = f2bu(v);
                } else if (mode == 0) {
                    ((u16*)C)[(size_t)m * N + n] = f2bu(v);
                } else if (mode == 1) {
                    ((u16*)C)[(size_t)m * N + n] = f2bu(v + bu2f(((const u16*)res)[(size_t)m * N + n]));
                } else if (mode == 2) {
                    ((float*)C)[(size_t)m * N + n] = 2.f * v;
                } else {  // mode 4
                    ((float*)C)[(size_t)m * N + n] = v + ((const float*)res)[(size_t)m * N + n];
                }
            }
}

// ---------------------------------------------------------------- fused differential flash attention
// Q,K bf16: (B*T, 2048) col = h*128 + comp*64 + d ; Vt bf16: (B,H,64,S) ; O bf16: (B*T, 1024)
template <bool CAUSAL>
__global__ __launch_bounds__(256, 2)
void diff_flash(const u16* __restrict__ Q, const u16* __restrict__ Kg, const u16* __restrict__ Vt,
                u16* __restrict__ O, const float* __restrict__ lq1, const float* __restrict__ lk1,
                const float* __restrict__ lq2, const float* __restrict__ lk2, int T, int S) {
    __shared__ u16 sK1[32 * 64];
    __shared__ u16 sK2[32 * 64];
    __shared__ u16 sV[64 * 32];
    __shared__ u16 sP[4][16 * 32];

    const int tid = threadIdx.x;
    const int w = tid >> 6, lane = tid & 63, q4 = lane >> 4, l16 = lane & 15;
    const int b = blockIdx.z, h = blockIdx.y, t0 = blockIdx.x * 64;
    const f32x4 fzero = {0.f, 0.f, 0.f, 0.f};

    float d1 = 0.f, d2 = 0.f;
    for (int d = 0; d < 64; ++d) {
        d1 += lq1[h * 64 + d] * lk1[h * 64 + d];
        d2 += lq2[h * 64 + d] * lk2[h * 64 + d];
    }
    const float lam = __expf(d1) - __expf(d2) + 0.8f;

    s16x8 qf[2][2];
    {
        const size_t qrow = (size_t)(b * T + t0 + w * 16 + l16) * 2048 + h * 128;
#pragma unroll
        for (int c = 0; c < 2; ++c)
#pragma unroll
            for (int kk = 0; kk < 2; ++kk)
                qf[c][kk] = *(const s16x8*)&Q[qrow + c * 64 + kk * 32 + q4 * 8];
    }

    f32x4 o1[4], o2[4];
    float ms1[4], ls1[4], ms2[4], ls2[4];
#pragma unroll
    for (int jn = 0; jn < 4; ++jn) { o1[jn] = fzero; o2[jn] = fzero; }
#pragma unroll
    for (int r = 0; r < 4; ++r) { ms1[r] = ms2[r] = -1e30f; ls1[r] = ls2[r] = 0.f; }

    const int s_end = CAUSAL ? (t0 + 64) : S;
    for (int s0 = 0; s0 < s_end; s0 += 32) {
        {
            int rk = tid >> 3, ck = (tid & 7) * 8;
            const size_t krow = (size_t)(b * S + s0 + rk) * 2048 + h * 128 + ck;
            gld_lds16(&Kg[krow], &sK1[tid * 8]);
            gld_lds16(&Kg[krow + 64], &sK2[tid * 8]);
            int rv = tid >> 2, cv = (tid & 3) * 8;
            gld_lds16(&Vt[(size_t)((b * 16 + h) * 64 + rv) * S + s0 + cv], &sV[tid * 8]);
        }
        WAIT_VM0();
        __syncthreads();

        auto comp_step = [&](const u16* sK, const s16x8* qfc, float* m, float* l, f32x4* o) {
            f32x4 sc[2];
            sc[0] = fzero; sc[1] = fzero;
#pragma unroll
            for (int j = 0; j < 2; ++j)
#pragma unroll
                for (int kk = 0; kk < 2; ++kk) {
                    s16x8 kf = *(const s16x8*)&sK[(j * 16 + l16) * 64 + kk * 32 + q4 * 8];
                    sc[j] = __builtin_amdgcn_mfma_f32_16x16x32_bf16(qfc[kk], kf, sc[j], 0, 0, 0);
                }
            float p[2][4];
#pragma unroll
            for (int j = 0; j < 2; ++j)
#pragma unroll
                for (int r = 0; r < 4; ++r) {
                    float v = sc[j][r] * 0.125f;
                    if (CAUSAL && (s0 + j * 16 + l16 > t0 + w * 16 + q4 * 4 + r)) v = -1e9f;
                    p[j][r] = v;
                }
            float mx[4];
#pragma unroll
            for (int r = 0; r < 4; ++r) mx[r] = fmaxf(p[0][r], p[1][r]);
#pragma unroll
            for (int off = 8; off; off >>= 1)
#pragma unroll
                for (int r = 0; r < 4; ++r) mx[r] = fmaxf(mx[r], __shfl_xor(mx[r], off, 16));
            float alpha[4];
#pragma unroll
            for (int r = 0; r < 4; ++r) {
                float mn = fmaxf(m[r], mx[r]);
                alpha[r] = __expf(m[r] - mn);
                m[r] = mn;
            }
            float rs[4];
#pragma unroll
            for (int r = 0; r < 4; ++r) {
                p[0][r] = __expf(p[0][r] - m[r]);
                p[1][r] = __expf(p[1][r] - m[r]);
                rs[r] = p[0][r] + p[1][r];
            }
#pragma unroll
            for (int off = 8; off; off >>= 1)
#pragma unroll
                for (int r = 0; r < 4; ++r) rs[r] += __shfl_xor(rs[r], off, 16);
#pragma unroll
            for (int r = 0; r < 4; ++r) l[r] = l[r] * alpha[r] + rs[r];
#pragma unroll
            for (int jn = 0; jn < 4; ++jn)
#pragma unroll
                for (int r = 0; r < 4; ++r) o[jn][r] *= alpha[r];
#pragma unroll
            for (int j = 0; j < 2; ++j)
#pragma unroll
                for (int r = 0; r < 4; ++r)
                    sP[w][(q4 * 4 + r) * 32 + j * 16 + l16] = f2bu(p[j][r]);
            WAIT_LGKM0();
            s16x8 pa = *(const s16x8*)&sP[w][l16 * 32 + q4 * 8];
#pragma unroll
            for (int jn = 0; jn < 4; ++jn) {
                s16x8 vf = *(const s16x8*)&sV[(jn * 16 + l16) * 32 + q4 * 8];
                o[jn] = __builtin_amdgcn_mfma_f32_16x16x32_bf16(pa, vf, o[jn], 0, 0, 0);
            }
            MEMBAR();
        };
        comp_step(sK1, qf[0], ms1, ls1, o1);
        comp_step(sK2, qf[1], ms2, ls2, o2);
        __syncthreads();
    }

    float inv1[4], inv2[4];
#pragma unroll
    for (int r = 0; r < 4; ++r) { inv1[r] = 1.f / ls1[r]; inv2[r] = lam / ls2[r]; }
    float val[4][4];
    float ss[4] = {0.f, 0.f, 0.f, 0.f};
#pragma unroll
    for (int jn = 0; jn < 4; ++jn)
#pragma unroll
        for (int r = 0; r < 4; ++r) {
            float v = o1[jn][r] * inv1[r] - o2[jn][r] * inv2[r];
            val[jn][r] = v;
            ss[r] += v * v;
        }
#pragma unroll
    for (int off = 8; off; off >>= 1)
#pragma unroll
        for (int r = 0; r < 4; ++r) ss[r] += __shfl_xor(ss[r], off, 16);
#pragma unroll
    for (int r = 0; r < 4; ++r) ss[r] = rsqrtf(ss[r] * (1.f / 64.f) + 1e-6f) * 0.2f;
#pragma unroll
    for (int jn = 0; jn < 4; ++jn)
#pragma unroll
        for (int r = 0; r < 4; ++r)
            O[(size_t)(b * T + t0 + w * 16 + q4 * 4 + r) * 1024 + h * 64 + jn * 16 + l16] =
                f2bu(val[jn][r] * ss[r]);
}

// ---------------------------------------------------------------- launch
extern "C" void kernel_launch(void* const* d_in, const int* in_sizes, int n_in,
                              void* d_out, int out_size, void* d_ws, size_t ws_size,
                              hipStream_t stream) {
    (void)in_sizes; (void)n_in; (void)out_size; (void)ws_size;
    const float* x     = (const float*)d_in[0];
    const float* enc   = (const float*)d_in[1];
    const float* Wq_s  = (const float*)d_in[2];
    const float* Wk_s  = (const float*)d_in[3];
    const float* Wv_s  = (const float*)d_in[4];
    const float* Wo_s  = (const float*)d_in[5];
    const float* lq1_s = (const float*)d_in[6];
    const float* lk1_s = (const float*)d_in[7];
    const float* lq2_s = (const float*)d_in[8];
    const float* lk2_s = (const float*)d_in[9];
    const float* Wq_c  = (const float*)d_in[10];
    const float* Wk_c  = (const float*)d_in[11];
    const float* Wv_c  = (const float*)d_in[12];
    const float* Wo_c  = (const float*)d_in[13];
    const float* lq1_c = (const float*)d_in[14];
    const float* lk1_c = (const float*)d_in[15];
    const float* lq2_c = (const float*)d_in[16];
    const float* lk2_c = (const float*)d_in[17];
    const float* g_rms = (const float*)d_in[18];
    const float* W1    = (const float*)d_in[19];
    const float* W2    = (const float*)d_in[20];
    const float* W3    = (const float*)d_in[21];

    char* ws = (char*)d_ws;
    size_t off = 0;
    auto ab = [&](size_t bytes) -> void* { void* p = ws + off; off += bytes; return p; };
    // bf16 transposed weights (48 MB)
    u16* WqTs = (u16*)ab((size_t)2048 * 1024 * 2);
    u16* WkTs = (u16*)ab((size_t)2048 * 1024 * 2);
    u16* WvTs = (u16*)ab((size_t)1024 * 1024 * 2);
    u16* WoTs = (u16*)ab((size_t)1024 * 1024 * 2);
    u16* WqTc = (u16*)ab((size_t)2048 * 1024 * 2);
    u16* WkTc = (u16*)ab((size_t)2048 * 1024 * 2);
    u16* WvTc = (u16*)ab((size_t)1024 * 1024 * 2);
    u16* WoTc = (u16*)ab((size_t)1024 * 1024 * 2);
    u16* W1T  = (u16*)ab((size_t)4096 * 1024 * 2);
    u16* W2T  = (u16*)ab((size_t)4096 * 1024 * 2);
    u16* W3T  = (u16*)ab((size_t)1024 * 4096 * 2);
    // activation pool (these die before FFN; fa/fb reuse the space)
    char* pool = ws + off;
    u16* h0   = (u16*)ab((size_t)4096 * 1024 * 2);
    u16* encb = (u16*)ab((size_t)4096 * 1024 * 2);
    u16* Qb   = (u16*)ab((size_t)4096 * 2048 * 2);
    u16* Kb   = (u16*)ab((size_t)4096 * 2048 * 2);
    u16* Vt   = (u16*)ab((size_t)4096 * 1024 * 2);
    u16* Ob   = (u16*)ab((size_t)4096 * 1024 * 2);
    u16* fa   = (u16*)pool;                                   // 32 MB (h0+encb+Qb)
    u16* fb   = (u16*)(pool + (size_t)4096 * 4096 * 2);       // 32 MB (Kb+Vt+Ob)
    u16* h1   = (u16*)ab((size_t)4096 * 1024 * 2);            // bf16
    float* h2 = (float*)ab((size_t)4096 * 1024 * 4);          // f32
    u16* rn   = (u16*)ab((size_t)4096 * 1024 * 2);            // bf16

    dim3 tb(32, 8);
    transpose_k<<<dim3(64, 32), tb, 0, stream>>>(Wq_s, WqTs, 1024, 2048);
    transpose_k<<<dim3(64, 32), tb, 0, stream>>>(Wk_s, WkTs, 1024, 2048);
    transpose_k<<<dim3(32, 32), tb, 0, stream>>>(Wv_s, WvTs, 1024, 1024);
    transpose_k<<<dim3(32, 32), tb, 0, stream>>>(Wo_s, WoTs, 1024, 1024);
    transpose_k<<<dim3(64, 32), tb, 0, stream>>>(Wq_c, WqTc, 1024, 2048);
    transpose_k<<<dim3(64, 32), tb, 0, stream>>>(Wk_c, WkTc, 1024, 2048);
    transpose_k<<<dim3(32, 32), tb, 0, stream>>>(Wv_c, WvTc, 1024, 1024);
    transpose_k<<<dim3(32, 32), tb, 0, stream>>>(Wo_c, WoTc, 1024, 1024);
    transpose_k<<<dim3(128, 32), tb, 0, stream>>>(W1, W1T, 1024, 4096);
    transpose_k<<<dim3(128, 32), tb, 0, stream>>>(W2, W2T, 1024, 4096);
    transpose_k<<<dim3(32, 128), tb, 0, stream>>>(W3, W3T, 4096, 1024);

    rmsnorm_k<<<4096, 256, 0, stream>>>(x, g_rms, h0);
    convert_k<<<4096, 256, 0, stream>>>(enc, encb, 4096 * 1024 / 4);

    // self attention (causal); residual = h0 (normed input, per reference)
    gemm_bt<<<dim3(16, 32), 256, 0, stream>>>(h0, WqTs, Qb, nullptr, 4096, 2048, 1024, 0);
    gemm_bt<<<dim3(16, 32), 256, 0, stream>>>(h0, WkTs, Kb, nullptr, 4096, 2048, 1024, 0);
    gemm_bt<<<dim3(8, 32), 256, 0, stream>>>(h0, WvTs, Vt, nullptr, 4096, 1024, 1024, 3);
    diff_flash<true><<<dim3(16, 16, 4), 256, 0, stream>>>(Qb, Kb, Vt, Ob, lq1_s, lk1_s, lq2_s, lk2_s, 1024, 1024);
    gemm_bt<<<dim3(8, 32), 256, 0, stream>>>(Ob, WoTs, h1, h0, 4096, 1024, 1024, 1);

    // cross attention (non-causal), output replaces h; then h = h + h  (2x in epilogue)
    gemm_bt<<<dim3(16, 32), 256, 0, stream>>>(h1, WqTc, Qb, nullptr, 4096, 2048, 1024, 0);
    gemm_bt<<<dim3(16, 32), 256, 0, stream>>>(encb, WkTc, Kb, nullptr, 4096, 2048, 1024, 0);
    gemm_bt<<<dim3(8, 32), 256, 0, stream>>>(encb, WvTc, Vt, nullptr, 4096, 1024, 1024, 3);
    diff_flash<false><<<dim3(16, 16, 4), 256, 0, stream>>>(Qb, Kb, Vt, Ob, lq1_c, lk1_c, lq2_c, lk2_c, 1024, 1024);
    gemm_bt<<<dim3(8, 32), 256, 0, stream>>>(Ob, WoTc, h2, nullptr, 4096, 1024, 1024, 2);

    // FFN: out = (silu(rn@W1) * (rn@W2)) @ W3 + h2
    rmsnorm_k<<<4096, 256, 0, stream>>>(h2, g_rms, rn);
    gemm_bt<<<dim3(32, 32), 256, 0, stream>>>(rn, W1T, fa, nullptr, 4096, 4096, 1024, 0);
    gemm_bt<<<dim3(32, 32), 256, 0, stream>>>(rn, W2T, fb, nullptr, 4096, 4096, 1024, 0);
    silumul_k<<<16384, 256, 0, stream>>>(fa, fb, fa, 4096 * 4096 / 4);
    gemm_bt<<<dim3(8, 32), 256, 0, stream>>>(fa, W3T, (float*)d_out, h2, 4096, 1024, 4096, 4);
}

// Round 3
// 870.487 us; speedup vs baseline: 1.1738x; 1.1738x over previous
//
#include <hip/hip_runtime.h>

typedef __attribute__((ext_vector_type(8))) short s16x8;
typedef __attribute__((ext_vector_type(4))) float f32x4;
typedef unsigned short u16;

__device__ __forceinline__ float bu2f(u16 u) {
    union { unsigned int i; float f; } x; x.i = ((unsigned int)u) << 16; return x.f;
}
__device__ __forceinline__ u16 f2bu(float f) {
    union { float f; unsigned int i; } x; x.f = f;
    unsigned int r = x.i + 0x7fffu + ((x.i >> 16) & 1u);   // RNE
    return (u16)(r >> 16);
}

__device__ __forceinline__ void gld_lds16(const void* g, void* l) {
    __builtin_amdgcn_global_load_lds(
        (const __attribute__((address_space(1))) unsigned int*)g,
        (__attribute__((address_space(3))) unsigned int*)l, 16, 0, 0);
}
#define WAIT_VM0()   asm volatile("s_waitcnt vmcnt(0)" ::: "memory")
#define WAIT_LGKM0() asm volatile("s_waitcnt lgkmcnt(0)" ::: "memory")
#define MEMBAR()     asm volatile("" ::: "memory")

// ---------------------------------------------------------------- transpose + f32->bf16
__global__ __launch_bounds__(256)
void transpose_k(const float* __restrict__ src, u16* __restrict__ dst, int R, int C) {
    __shared__ u16 t[32][33];
    int bx = blockIdx.x * 32, by = blockIdx.y * 32;
    int x = bx + threadIdx.x;
#pragma unroll
    for (int k = 0; k < 4; ++k)
        t[threadIdx.y + k * 8][threadIdx.x] = f2bu(src[(size_t)(by + threadIdx.y + k * 8) * C + x]);
    __syncthreads();
    int x2 = by + threadIdx.x;
#pragma unroll
    for (int k = 0; k < 4; ++k)
        dst[(size_t)(bx + threadIdx.y + k * 8) * R + x2] = t[threadIdx.x][threadIdx.y + k * 8];
}

// ---------------------------------------------------------------- f32 -> bf16 convert
__global__ __launch_bounds__(256)
void convert_k(const float* __restrict__ a, u16* __restrict__ o, int n4) {
    int i = blockIdx.x * 256 + threadIdx.x;
    if (i >= n4) return;
    float4 v = ((const float4*)a)[i];
    ushort4 u;
    u.x = f2bu(v.x); u.y = f2bu(v.y); u.z = f2bu(v.z); u.w = f2bu(v.w);
    ((ushort4*)o)[i] = u;
}

// ---------------------------------------------------------------- rmsnorm (row = 1024), f32 in -> bf16 out
__global__ __launch_bounds__(256)
void rmsnorm_k(const float* __restrict__ x, const float* __restrict__ g, u16* __restrict__ y) {
    const int row = blockIdx.x, tid = threadIdx.x;
    float4 v = ((const float4*)(x + (size_t)row * 1024))[tid];
    float ss = v.x * v.x + v.y * v.y + v.z * v.z + v.w * v.w;
#pragma unroll
    for (int off = 32; off; off >>= 1) ss += __shfl_xor(ss, off, 64);
    __shared__ float red[4];
    if ((tid & 63) == 0) red[tid >> 6] = ss;
    __syncthreads();
    float tot = red[0] + red[1] + red[2] + red[3];
    float sc = rsqrtf(tot * (1.f / 1024.f) + 1e-6f);
    float4 gv = ((const float4*)g)[tid];
    ushort4 o;
    o.x = f2bu(v.x * sc * gv.x);
    o.y = f2bu(v.y * sc * gv.y);
    o.z = f2bu(v.z * sc * gv.z);
    o.w = f2bu(v.w * sc * gv.w);
    ((ushort4*)(y + (size_t)row * 1024))[tid] = o;
}

// ---------------------------------------------------------------- silu(a)*b  (bf16)
__global__ __launch_bounds__(256)
void silumul_k(const u16* __restrict__ a, const u16* __restrict__ b, u16* __restrict__ o, int n4) {
    int i = blockIdx.x * 256 + threadIdx.x;
    if (i >= n4) return;
    ushort4 ua = ((const ushort4*)a)[i], ub = ((const ushort4*)b)[i];
    ushort4 uo;
    {
        float v = bu2f(ua.x); uo.x = f2bu(v / (1.f + __expf(-v)) * bu2f(ub.x));
        v = bu2f(ua.y); uo.y = f2bu(v / (1.f + __expf(-v)) * bu2f(ub.y));
        v = bu2f(ua.z); uo.z = f2bu(v / (1.f + __expf(-v)) * bu2f(ub.z));
        v = bu2f(ua.w); uo.w = f2bu(v / (1.f + __expf(-v)) * bu2f(ub.w));
    }
    ((ushort4*)o)[i] = uo;
}

// ---------------------------------------------------------------- GEMM  C(M,N) = A(M,K) @ Bt(N,K)^T
// Tile TMx128. modes:
//  0: bf16 C[m*N+n]=acc       1: bf16 C=acc+bf16 res     2: f32 C=2*acc
//  4: f32 C=acc+f32 res
//  5: QKV routing (self): n<2048->Qb  n<4096->Kb  else V^T  (C = Qb base, contiguous)
//  6: KV routing (cross): n<2048->Kb  else V^T             (C = Kb base, contiguous)
//  7: W1/W2 routing:      n<4096->fa  else fb              (C = fa base, contiguous)
template <int TM>
__global__ __launch_bounds__(256, 2)
void gemm_bt(const u16* __restrict__ A, const u16* __restrict__ Bt, void* __restrict__ C,
             const void* __restrict__ res, int M, int N, int K, int mode) {
    constexpr int MI = TM / 32;  // 16x16 m-subtiles per wave
    __shared__ u16 sA[TM * 32];
    __shared__ u16 sB[128 * 32];
    const int tid = threadIdx.x;
    const int w = tid >> 6, lane = tid & 63, q4 = lane >> 4, l16 = lane & 15;
    const int m0 = blockIdx.y * TM, n0 = blockIdx.x * 128;
    const int wm = (w >> 1) * (TM / 2), wn = (w & 1) * 64;

    const f32x4 fzero = {0.f, 0.f, 0.f, 0.f};
    f32x4 acc[MI][4];
#pragma unroll
    for (int i = 0; i < MI; ++i)
#pragma unroll
        for (int j = 0; j < 4; ++j) acc[i][j] = fzero;

    const int r0 = tid >> 2, c0 = (tid & 3) * 8;  // 16B chunk per thread

    for (int k0 = 0; k0 < K; k0 += 32) {
        gld_lds16(A + (size_t)(m0 + r0) * K + k0 + c0, &sA[tid * 8]);
        if (TM == 128)
            gld_lds16(A + (size_t)(m0 + 64 + r0) * K + k0 + c0, &sA[(256 + tid) * 8]);
        gld_lds16(Bt + (size_t)(n0 + r0) * K + k0 + c0, &sB[tid * 8]);
        gld_lds16(Bt + (size_t)(n0 + 64 + r0) * K + k0 + c0, &sB[(256 + tid) * 8]);
        WAIT_VM0();
        __syncthreads();
        s16x8 af[MI], bfr[4];
#pragma unroll
        for (int i = 0; i < MI; ++i) af[i] = *(const s16x8*)&sA[(wm + i * 16 + l16) * 32 + q4 * 8];
#pragma unroll
        for (int j = 0; j < 4; ++j) bfr[j] = *(const s16x8*)&sB[(wn + j * 16 + l16) * 32 + q4 * 8];
#pragma unroll
        for (int i = 0; i < MI; ++i)
#pragma unroll
            for (int j = 0; j < 4; ++j)
                acc[i][j] = __builtin_amdgcn_mfma_f32_16x16x32_bf16(af[i], bfr[j], acc[i][j], 0, 0, 0);
        __syncthreads();
    }

    const size_t QBSZ = (size_t)4096 * 2048;   // elems
    const size_t FSZ  = (size_t)4096 * 4096;
#pragma unroll
    for (int i = 0; i < MI; ++i)
#pragma unroll
        for (int j = 0; j < 4; ++j)
#pragma unroll
            for (int r = 0; r < 4; ++r) {
                int m = m0 + wm + i * 16 + q4 * 4 + r;
                int n = n0 + wn + j * 16 + l16;
                float v = acc[i][j][r];
                if (mode == 0) {
                    ((u16*)C)[(size_t)m * N + n] = f2bu(v);
                } else if (mode == 1) {
                    ((u16*)C)[(size_t)m * N + n] = f2bu(v + bu2f(((const u16*)res)[(size_t)m * N + n]));
                } else if (mode == 2) {
                    ((float*)C)[(size_t)m * N + n] = 2.f * v;
                } else if (mode == 4) {
                    ((float*)C)[(size_t)m * N + n] = v + ((const float*)res)[(size_t)m * N + n];
                } else if (mode == 5) {
                    if (n < 2048) ((u16*)C)[(size_t)m * 2048 + n] = f2bu(v);
                    else if (n < 4096) ((u16*)C)[QBSZ + (size_t)m * 2048 + (n - 2048)] = f2bu(v);
                    else {
                        int nn = n - 4096, hh = nn >> 6, d = nn & 63, b = m >> 10, s = m & 1023;
                        ((u16*)C)[2 * QBSZ + ((size_t)((b * 16 + hh) * 64 + d)) * 1024 + s] = f2bu(v);
                    }
                } else if (mode == 6) {
                    if (n < 2048) ((u16*)C)[(size_t)m * 2048 + n] = f2bu(v);
                    else {
                        int nn = n - 2048, hh = nn >> 6, d = nn & 63, b = m >> 10, s = m & 1023;
                        ((u16*)C)[QBSZ + ((size_t)((b * 16 + hh) * 64 + d)) * 1024 + s] = f2bu(v);
                    }
                } else {  // 7
                    if (n < 4096) ((u16*)C)[(size_t)m * 4096 + n] = f2bu(v);
                    else ((u16*)C)[FSZ + (size_t)m * 4096 + (n - 4096)] = f2bu(v);
                }
            }
}

// ---------------------------------------------------------------- fused differential flash attention v2
// Q,K bf16: (B*T, 2048) col = h*128 + comp*64 + d ; Vt bf16: (B,H,64,S) ; O bf16: (B*T,1024)
// grid (h, b, t-block). S-tile 64, double-buffered staging, 1 barrier per tile.
template <bool CAUSAL>
__global__ __launch_bounds__(256, 2)
void diff_flash(const u16* __restrict__ Q, const u16* __restrict__ Kg, const u16* __restrict__ Vt,
                u16* __restrict__ O, const float* __restrict__ lq1, const float* __restrict__ lk1,
                const float* __restrict__ lq2, const float* __restrict__ lk2, int T, int S) {
    __shared__ u16 sK1[2][64 * 64];
    __shared__ u16 sK2[2][64 * 64];
    __shared__ u16 sV[2][64 * 64];
    __shared__ u16 sP[4][16 * 72];   // stride 72: pad kills 4-way store conflicts, keeps 16B-aligned reads

    const int tid = threadIdx.x;
    const int w = tid >> 6, lane = tid & 63, q4 = lane >> 4, l16 = lane & 15;
    const int h = blockIdx.x, b = blockIdx.y, zt = blockIdx.z, t0 = zt * 64;
    const f32x4 fzero = {0.f, 0.f, 0.f, 0.f};

    float d1 = 0.f, d2 = 0.f;
    for (int d = 0; d < 64; ++d) {
        d1 += lq1[h * 64 + d] * lk1[h * 64 + d];
        d2 += lq2[h * 64 + d] * lk2[h * 64 + d];
    }
    const float lam = __expf(d1) - __expf(d2) + 0.8f;

    s16x8 qf[2][2];
    {
        const size_t qrow = (size_t)(b * T + t0 + w * 16 + l16) * 2048 + h * 128;
#pragma unroll
        for (int c = 0; c < 2; ++c)
#pragma unroll
            for (int kk = 0; kk < 2; ++kk)
                qf[c][kk] = *(const s16x8*)&Q[qrow + c * 64 + kk * 32 + q4 * 8];
    }

    f32x4 o1[4], o2[4];
    float ms1[4], ls1[4], ms2[4], ls2[4];
#pragma unroll
    for (int jn = 0; jn < 4; ++jn) { o1[jn] = fzero; o2[jn] = fzero; }
#pragma unroll
    for (int r = 0; r < 4; ++r) { ms1[r] = ms2[r] = -1e30f; ls1[r] = ls2[r] = 0.f; }

    const int ntiles = CAUSAL ? (zt + 1) : (S / 64);
    const int rk = tid >> 3, ck = (tid & 7) * 8;

    auto stage = [&](int buf, int s0) {
        const size_t kb = (size_t)(b * S + s0 + rk) * 2048 + h * 128 + ck;
        gld_lds16(&Kg[kb], &sK1[buf][tid * 8]);
        gld_lds16(&Kg[kb + (size_t)32 * 2048], &sK1[buf][(256 + tid) * 8]);
        gld_lds16(&Kg[kb + 64], &sK2[buf][tid * 8]);
        gld_lds16(&Kg[kb + (size_t)32 * 2048 + 64], &sK2[buf][(256 + tid) * 8]);
        const size_t vb = (size_t)((b * 16 + h) * 64 + rk) * 1024 + s0 + ck;
        gld_lds16(&Vt[vb], &sV[buf][tid * 8]);
        gld_lds16(&Vt[vb + (size_t)32 * 1024], &sV[buf][(256 + tid) * 8]);
    };

    stage(0, 0);
    for (int it = 0; it < ntiles; ++it) {
        WAIT_VM0();
        __syncthreads();
        if (it + 1 < ntiles) stage((it + 1) & 1, (it + 1) * 64);
        const int buf = it & 1, s0 = it * 64;
        const bool diag = CAUSAL && (it == ntiles - 1);

        auto comp_step = [&](const u16* sK, const u16* sVb, const s16x8* qfc,
                             float* m, float* l, f32x4* o) {
            f32x4 sc[4];
#pragma unroll
            for (int j = 0; j < 4; ++j) sc[j] = fzero;
#pragma unroll
            for (int j = 0; j < 4; ++j)
#pragma unroll
                for (int kk = 0; kk < 2; ++kk) {
                    s16x8 kf = *(const s16x8*)&sK[(j * 16 + l16) * 64 + kk * 32 + q4 * 8];
                    sc[j] = __builtin_amdgcn_mfma_f32_16x16x32_bf16(qfc[kk], kf, sc[j], 0, 0, 0);
                }
            float p[4][4];
#pragma unroll
            for (int j = 0; j < 4; ++j)
#pragma unroll
                for (int r = 0; r < 4; ++r) {
                    float v = sc[j][r] * 0.125f;
                    if (diag && (s0 + j * 16 + l16 > t0 + w * 16 + q4 * 4 + r)) v = -1e9f;
                    p[j][r] = v;
                }
            float mx[4];
#pragma unroll
            for (int r = 0; r < 4; ++r)
                mx[r] = fmaxf(fmaxf(p[0][r], p[1][r]), fmaxf(p[2][r], p[3][r]));
#pragma unroll
            for (int off = 8; off; off >>= 1)
#pragma unroll
                for (int r = 0; r < 4; ++r) mx[r] = fmaxf(mx[r], __shfl_xor(mx[r], off, 16));
            float alpha[4];
#pragma unroll
            for (int r = 0; r < 4; ++r) {
                float mn = fmaxf(m[r], mx[r]);
                alpha[r] = __expf(m[r] - mn);
                m[r] = mn;
            }
            float rs[4];
#pragma unroll
            for (int r = 0; r < 4; ++r) {
                float s0r = 0.f;
#pragma unroll
                for (int j = 0; j < 4; ++j) { p[j][r] = __expf(p[j][r] - m[r]); s0r += p[j][r]; }
                rs[r] = s0r;
            }
#pragma unroll
            for (int off = 8; off; off >>= 1)
#pragma unroll
                for (int r = 0; r < 4; ++r) rs[r] += __shfl_xor(rs[r], off, 16);
#pragma unroll
            for (int r = 0; r < 4; ++r) l[r] = l[r] * alpha[r] + rs[r];
#pragma unroll
            for (int jn = 0; jn < 4; ++jn)
#pragma unroll
                for (int r = 0; r < 4; ++r) o[jn][r] *= alpha[r];
#pragma unroll
            for (int j = 0; j < 4; ++j)
#pragma unroll
                for (int r = 0; r < 4; ++r)
                    sP[w][(q4 * 4 + r) * 72 + j * 16 + l16] = f2bu(p[j][r]);
            WAIT_LGKM0();
            s16x8 pa0 = *(const s16x8*)&sP[w][l16 * 72 + q4 * 8];
            s16x8 pa1 = *(const s16x8*)&sP[w][l16 * 72 + 32 + q4 * 8];
#pragma unroll
            for (int jn = 0; jn < 4; ++jn) {
                s16x8 vf0 = *(const s16x8*)&sVb[(jn * 16 + l16) * 64 + q4 * 8];
                o[jn] = __builtin_amdgcn_mfma_f32_16x16x32_bf16(pa0, vf0, o[jn], 0, 0, 0);
                s16x8 vf1 = *(const s16x8*)&sVb[(jn * 16 + l16) * 64 + 32 + q4 * 8];
                o[jn] = __builtin_amdgcn_mfma_f32_16x16x32_bf16(pa1, vf1, o[jn], 0, 0, 0);
            }
            MEMBAR();
        };
        comp_step(sK1[buf], sV[buf], qf[0], ms1, ls1, o1);
        comp_step(sK2[buf], sV[buf], qf[1], ms2, ls2, o2);
    }

    float inv1[4], inv2[4];
#pragma unroll
    for (int r = 0; r < 4; ++r) { inv1[r] = 1.f / ls1[r]; inv2[r] = lam / ls2[r]; }
    float val[4][4];
    float ss[4] = {0.f, 0.f, 0.f, 0.f};
#pragma unroll
    for (int jn = 0; jn < 4; ++jn)
#pragma unroll
        for (int r = 0; r < 4; ++r) {
            float v = o1[jn][r] * inv1[r] - o2[jn][r] * inv2[r];
            val[jn][r] = v;
            ss[r] += v * v;
        }
#pragma unroll
    for (int off = 8; off; off >>= 1)
#pragma unroll
        for (int r = 0; r < 4; ++r) ss[r] += __shfl_xor(ss[r], off, 16);
#pragma unroll
    for (int r = 0; r < 4; ++r) ss[r] = rsqrtf(ss[r] * (1.f / 64.f) + 1e-6f) * 0.2f;
#pragma unroll
    for (int jn = 0; jn < 4; ++jn)
#pragma unroll
        for (int r = 0; r < 4; ++r)
            O[(size_t)(b * T + t0 + w * 16 + q4 * 4 + r) * 1024 + h * 64 + jn * 16 + l16] =
                f2bu(val[jn][r] * ss[r]);
}

// ---------------------------------------------------------------- launch
extern "C" void kernel_launch(void* const* d_in, const int* in_sizes, int n_in,
                              void* d_out, int out_size, void* d_ws, size_t ws_size,
                              hipStream_t stream) {
    (void)in_sizes; (void)n_in; (void)out_size; (void)ws_size;
    const float* x     = (const float*)d_in[0];
    const float* enc   = (const float*)d_in[1];
    const float* Wq_s  = (const float*)d_in[2];
    const float* Wk_s  = (const float*)d_in[3];
    const float* Wv_s  = (const float*)d_in[4];
    const float* Wo_s  = (const float*)d_in[5];
    const float* lq1_s = (const float*)d_in[6];
    const float* lk1_s = (const float*)d_in[7];
    const float* lq2_s = (const float*)d_in[8];
    const float* lk2_s = (const float*)d_in[9];
    const float* Wq_c  = (const float*)d_in[10];
    const float* Wk_c  = (const float*)d_in[11];
    const float* Wv_c  = (const float*)d_in[12];
    const float* Wo_c  = (const float*)d_in[13];
    const float* lq1_c = (const float*)d_in[14];
    const float* lk1_c = (const float*)d_in[15];
    const float* lq2_c = (const float*)d_in[16];
    const float* lk2_c = (const float*)d_in[17];
    const float* g_rms = (const float*)d_in[18];
    const float* W1    = (const float*)d_in[19];
    const float* W2    = (const float*)d_in[20];
    const float* W3    = (const float*)d_in[21];

    char* ws = (char*)d_ws;
    size_t off = 0;
    auto ab = [&](size_t elems) -> u16* { u16* p = (u16*)(ws + off); off += elems * 2; return p; };
    // transposed bf16 weights (concatenated for fused GEMMs)
    u16* WqkvTs = ab((size_t)5120 * 1024);   // [WqT;WkT;WvT]
    u16* WoTs   = ab((size_t)1024 * 1024);
    u16* WqTc   = ab((size_t)2048 * 1024);
    u16* WkvTc  = ab((size_t)3072 * 1024);   // [WkT;WvT]
    u16* WoTc   = ab((size_t)1024 * 1024);
    u16* W12T   = ab((size_t)8192 * 1024);   // [W1T;W2T]
    u16* W3T    = ab((size_t)1024 * 4096);
    // activation pool — fa/fb overlay the attention buffers (dead by FFN time)
    char* pool = ws + off;
    u16* h0   = ab((size_t)4096 * 1024);
    u16* encb = ab((size_t)4096 * 1024);
    u16* Qb   = ab((size_t)4096 * 2048);     // Qb,Kb,Vt contiguous (mode 5/6 routing)
    u16* Kb   = ab((size_t)4096 * 2048);
    u16* Vt   = ab((size_t)4096 * 1024);
    u16* Ob   = ab((size_t)4096 * 1024);
    u16* fa   = (u16*)pool;                              // 32MB = h0+encb+Qb
    u16* fb   = (u16*)(pool + (size_t)4096 * 4096 * 2);  // 32MB = Kb+Vt+Ob
    u16* h1   = ab((size_t)4096 * 1024);
    float* h2 = (float*)(ws + off); off += (size_t)4096 * 1024 * 4;
    u16* rn   = ab((size_t)4096 * 1024);

    dim3 tb(32, 8);
    transpose_k<<<dim3(64, 32), tb, 0, stream>>>(Wq_s, WqkvTs, 1024, 2048);
    transpose_k<<<dim3(64, 32), tb, 0, stream>>>(Wk_s, WqkvTs + (size_t)2048 * 1024, 1024, 2048);
    transpose_k<<<dim3(32, 32), tb, 0, stream>>>(Wv_s, WqkvTs + (size_t)4096 * 1024, 1024, 1024);
    transpose_k<<<dim3(32, 32), tb, 0, stream>>>(Wo_s, WoTs, 1024, 1024);
    transpose_k<<<dim3(64, 32), tb, 0, stream>>>(Wq_c, WqTc, 1024, 2048);
    transpose_k<<<dim3(64, 32), tb, 0, stream>>>(Wk_c, WkvTc, 1024, 2048);
    transpose_k<<<dim3(32, 32), tb, 0, stream>>>(Wv_c, WkvTc + (size_t)2048 * 1024, 1024, 1024);
    transpose_k<<<dim3(32, 32), tb, 0, stream>>>(Wo_c, WoTc, 1024, 1024);
    transpose_k<<<dim3(128, 32), tb, 0, stream>>>(W1, W12T, 1024, 4096);
    transpose_k<<<dim3(128, 32), tb, 0, stream>>>(W2, W12T + (size_t)4096 * 1024, 1024, 4096);
    transpose_k<<<dim3(32, 128), tb, 0, stream>>>(W3, W3T, 4096, 1024);

    rmsnorm_k<<<4096, 256, 0, stream>>>(x, g_rms, h0);
    convert_k<<<4096, 256, 0, stream>>>(enc, encb, 4096 * 1024 / 4);

    // self attention (causal); residual = h0 (normed input, per reference)
    gemm_bt<128><<<dim3(40, 32), 256, 0, stream>>>(h0, WqkvTs, Qb, nullptr, 4096, 5120, 1024, 5);
    diff_flash<true><<<dim3(16, 4, 16), 256, 0, stream>>>(Qb, Kb, Vt, Ob, lq1_s, lk1_s, lq2_s, lk2_s, 1024, 1024);
    gemm_bt<64><<<dim3(8, 64), 256, 0, stream>>>(Ob, WoTs, h1, h0, 4096, 1024, 1024, 1);

    // cross attention (non-causal); then h = h + h (2x folded in epilogue)
    gemm_bt<128><<<dim3(16, 32), 256, 0, stream>>>(h1, WqTc, Qb, nullptr, 4096, 2048, 1024, 0);
    gemm_bt<128><<<dim3(24, 32), 256, 0, stream>>>(encb, WkvTc, Kb, nullptr, 4096, 3072, 1024, 6);
    diff_flash<false><<<dim3(16, 4, 16), 256, 0, stream>>>(Qb, Kb, Vt, Ob, lq1_c, lk1_c, lq2_c, lk2_c, 1024, 1024);
    gemm_bt<64><<<dim3(8, 64), 256, 0, stream>>>(Ob, WoTc, h2, nullptr, 4096, 1024, 1024, 2);

    // FFN: out = (silu(rn@W1) * (rn@W2)) @ W3 + h2
    rmsnorm_k<<<4096, 256, 0, stream>>>(h2, g_rms, rn);
    gemm_bt<128><<<dim3(64, 32), 256, 0, stream>>>(rn, W12T, fa, nullptr, 4096, 8192, 1024, 7);
    silumul_k<<<16384, 256, 0, stream>>>(fa, fb, fa, 4096 * 4096 / 4);
    gemm_bt<64><<<dim3(8, 64), 256, 0, stream>>>(fa, W3T, (float*)d_out, h2, 4096, 1024, 4096, 4);
}

// Round 4
// 757.790 us; speedup vs baseline: 1.3484x; 1.1487x over previous
//
#include <hip/hip_runtime.h>

typedef __attribute__((ext_vector_type(8))) short s16x8;
typedef __attribute__((ext_vector_type(4))) float f32x4;
typedef unsigned short u16;

__device__ __forceinline__ float bu2f(u16 u) {
    union { unsigned int i; float f; } x; x.i = ((unsigned int)u) << 16; return x.f;
}
__device__ __forceinline__ u16 f2bu(float f) {
    union { float f; unsigned int i; } x; x.f = f;
    unsigned int r = x.i + 0x7fffu + ((x.i >> 16) & 1u);   // RNE
    return (u16)(r >> 16);
}

__device__ __forceinline__ void gld_lds16(const void* g, void* l) {
    __builtin_amdgcn_global_load_lds(
        (const __attribute__((address_space(1))) unsigned int*)g,
        (__attribute__((address_space(3))) unsigned int*)l, 16, 0, 0);
}
#define WAIT_VM0()   asm volatile("s_waitcnt vmcnt(0)" ::: "memory")
#define WAIT_LGKM0() asm volatile("s_waitcnt lgkmcnt(0)" ::: "memory")
#define MEMBAR()     asm volatile("" ::: "memory")

// ---------------------------------------------------------------- batched transpose + f32->bf16
// 4 source/dest pairs selected by blockIdx.z; src (R,C) -> dst (C,R)
__global__ __launch_bounds__(256)
void transpose4_k(const float* s0, const float* s1, const float* s2, const float* s3,
                  u16* d0, u16* d1, u16* d2, u16* d3, int R, int C) {
    const float* src = blockIdx.z == 0 ? s0 : blockIdx.z == 1 ? s1 : blockIdx.z == 2 ? s2 : s3;
    u16* dst = blockIdx.z == 0 ? d0 : blockIdx.z == 1 ? d1 : blockIdx.z == 2 ? d2 : d3;
    __shared__ u16 t[32][33];
    int bx = blockIdx.x * 32, by = blockIdx.y * 32;
    int x = bx + threadIdx.x;
#pragma unroll
    for (int k = 0; k < 4; ++k)
        t[threadIdx.y + k * 8][threadIdx.x] = f2bu(src[(size_t)(by + threadIdx.y + k * 8) * C + x]);
    __syncthreads();
    int x2 = by + threadIdx.x;
#pragma unroll
    for (int k = 0; k < 4; ++k)
        dst[(size_t)(bx + threadIdx.y + k * 8) * R + x2] = t[threadIdx.x][threadIdx.y + k * 8];
}

// ---------------------------------------------------------------- f32 -> bf16 convert
__global__ __launch_bounds__(256)
void convert_k(const float* __restrict__ a, u16* __restrict__ o, int n4) {
    int i = blockIdx.x * 256 + threadIdx.x;
    if (i >= n4) return;
    float4 v = ((const float4*)a)[i];
    ushort4 u;
    u.x = f2bu(v.x); u.y = f2bu(v.y); u.z = f2bu(v.z); u.w = f2bu(v.w);
    ((ushort4*)o)[i] = u;
}

// ---------------------------------------------------------------- rmsnorm (row = 1024), f32 in -> bf16 out
__global__ __launch_bounds__(256)
void rmsnorm_k(const float* __restrict__ x, const float* __restrict__ g, u16* __restrict__ y) {
    const int row = blockIdx.x, tid = threadIdx.x;
    float4 v = ((const float4*)(x + (size_t)row * 1024))[tid];
    float ss = v.x * v.x + v.y * v.y + v.z * v.z + v.w * v.w;
#pragma unroll
    for (int off = 32; off; off >>= 1) ss += __shfl_xor(ss, off, 64);
    __shared__ float red[4];
    if ((tid & 63) == 0) red[tid >> 6] = ss;
    __syncthreads();
    float tot = red[0] + red[1] + red[2] + red[3];
    float sc = rsqrtf(tot * (1.f / 1024.f) + 1e-6f);
    float4 gv = ((const float4*)g)[tid];
    ushort4 o;
    o.x = f2bu(v.x * sc * gv.x);
    o.y = f2bu(v.y * sc * gv.y);
    o.z = f2bu(v.z * sc * gv.z);
    o.w = f2bu(v.w * sc * gv.w);
    ((ushort4*)(y + (size_t)row * 1024))[tid] = o;
}

// ---------------------------------------------------------------- silu(a)*b  (bf16)
__global__ __launch_bounds__(256)
void silumul_k(const u16* __restrict__ a, const u16* __restrict__ b, u16* __restrict__ o, int n4) {
    int i = blockIdx.x * 256 + threadIdx.x;
    if (i >= n4) return;
    ushort4 ua = ((const ushort4*)a)[i], ub = ((const ushort4*)b)[i];
    ushort4 uo;
    {
        float v = bu2f(ua.x); uo.x = f2bu(v / (1.f + __expf(-v)) * bu2f(ub.x));
        v = bu2f(ua.y); uo.y = f2bu(v / (1.f + __expf(-v)) * bu2f(ub.y));
        v = bu2f(ua.z); uo.z = f2bu(v / (1.f + __expf(-v)) * bu2f(ub.z));
        v = bu2f(ua.w); uo.w = f2bu(v / (1.f + __expf(-v)) * bu2f(ub.w));
    }
    ((ushort4*)o)[i] = uo;
}

// ---------------------------------------------------------------- GEMM  C(M,N) = A(M,K) @ Bt(N,K)^T
// Tile TMx128. modes:
//  0: bf16 C[m*N+n]=acc       1: bf16 C=acc+bf16 res     2: f32 C=2*acc
//  4: f32 C=acc+f32 res
//  5: QKV routing (self): n<2048->Qb  n<4096->Kb  else V^T  (C = Qb base, contiguous)
//  6: KV routing (cross): n<2048->Kb  else V^T             (C = Kb base, contiguous)
//  7: W1/W2 routing:      n<4096->fa  else fb              (C = fa base, contiguous)
template <int TM>
__global__ __launch_bounds__(256, 2)
void gemm_bt(const u16* __restrict__ A, const u16* __restrict__ Bt, void* __restrict__ C,
             const void* __restrict__ res, int M, int N, int K, int mode) {
    constexpr int MI = TM / 32;
    __shared__ u16 sA[TM * 32];
    __shared__ u16 sB[128 * 32];
    const int tid = threadIdx.x;
    const int w = tid >> 6, lane = tid & 63, q4 = lane >> 4, l16 = lane & 15;
    const int m0 = blockIdx.y * TM, n0 = blockIdx.x * 128;
    const int wm = (w >> 1) * (TM / 2), wn = (w & 1) * 64;

    const f32x4 fzero = {0.f, 0.f, 0.f, 0.f};
    f32x4 acc[MI][4];
#pragma unroll
    for (int i = 0; i < MI; ++i)
#pragma unroll
        for (int j = 0; j < 4; ++j) acc[i][j] = fzero;

    const int r0 = tid >> 2, c0 = (tid & 3) * 8;

    for (int k0 = 0; k0 < K; k0 += 32) {
        gld_lds16(A + (size_t)(m0 + r0) * K + k0 + c0, &sA[tid * 8]);
        if (TM == 128)
            gld_lds16(A + (size_t)(m0 + 64 + r0) * K + k0 + c0, &sA[(256 + tid) * 8]);
        gld_lds16(Bt + (size_t)(n0 + r0) * K + k0 + c0, &sB[tid * 8]);
        gld_lds16(Bt + (size_t)(n0 + 64 + r0) * K + k0 + c0, &sB[(256 + tid) * 8]);
        WAIT_VM0();
        __syncthreads();
        s16x8 af[MI], bfr[4];
#pragma unroll
        for (int i = 0; i < MI; ++i) af[i] = *(const s16x8*)&sA[(wm + i * 16 + l16) * 32 + q4 * 8];
#pragma unroll
        for (int j = 0; j < 4; ++j) bfr[j] = *(const s16x8*)&sB[(wn + j * 16 + l16) * 32 + q4 * 8];
#pragma unroll
        for (int i = 0; i < MI; ++i)
#pragma unroll
            for (int j = 0; j < 4; ++j)
                acc[i][j] = __builtin_amdgcn_mfma_f32_16x16x32_bf16(af[i], bfr[j], acc[i][j], 0, 0, 0);
        __syncthreads();
    }

    const size_t QBSZ = (size_t)4096 * 2048;
    const size_t FSZ  = (size_t)4096 * 4096;
#pragma unroll
    for (int i = 0; i < MI; ++i)
#pragma unroll
        for (int j = 0; j < 4; ++j)
#pragma unroll
            for (int r = 0; r < 4; ++r) {
                int m = m0 + wm + i * 16 + q4 * 4 + r;
                int n = n0 + wn + j * 16 + l16;
                float v = acc[i][j][r];
                if (mode == 0) {
                    ((u16*)C)[(size_t)m * N + n] = f2bu(v);
                } else if (mode == 1) {
                    ((u16*)C)[(size_t)m * N + n] = f2bu(v + bu2f(((const u16*)res)[(size_t)m * N + n]));
                } else if (mode == 2) {
                    ((float*)C)[(size_t)m * N + n] = 2.f * v;
                } else if (mode == 4) {
                    ((float*)C)[(size_t)m * N + n] = v + ((const float*)res)[(size_t)m * N + n];
                } else if (mode == 5) {
                    if (n < 2048) ((u16*)C)[(size_t)m * 2048 + n] = f2bu(v);
                    else if (n < 4096) ((u16*)C)[QBSZ + (size_t)m * 2048 + (n - 2048)] = f2bu(v);
                    else {
                        int nn = n - 4096, hh = nn >> 6, d = nn & 63, b = m >> 10, s = m & 1023;
                        ((u16*)C)[2 * QBSZ + ((size_t)((b * 16 + hh) * 64 + d)) * 1024 + s] = f2bu(v);
                    }
                } else if (mode == 6) {
                    if (n < 2048) ((u16*)C)[(size_t)m * 2048 + n] = f2bu(v);
                    else {
                        int nn = n - 2048, hh = nn >> 6, d = nn & 63, b = m >> 10, s = m & 1023;
                        ((u16*)C)[QBSZ + ((size_t)((b * 16 + hh) * 64 + d)) * 1024 + s] = f2bu(v);
                    }
                } else {  // 7
                    if (n < 4096) ((u16*)C)[(size_t)m * 4096 + n] = f2bu(v);
                    else ((u16*)C)[FSZ + (size_t)m * 4096 + (n - 4096)] = f2bu(v);
                }
            }
}

// ---------------------------------------------------------------- fused differential flash attention v3
// Transposed-score formulation: Sc^T = K@Q^T (rows=s, cols=t); softmax over s is
// in-lane (16 vals) + 2 shuffles; P^T via 4x ds_write_b64 + 2x ds_read_b128;
// O accumulated transposed (rows=d, cols=t). LDS uses chunk-rotation
// (slot = (chunk+row)&7) so fragment reads hit all 32 banks uniformly while
// global_load_lds staging stays lane-contiguous (rotation applied to the
// *source* address instead).
// Q,K bf16: (B*T, 2048) col = h*128 + comp*64 + d ; Vt bf16: (B,H,64,S) ; O bf16: (B*T,1024)
template <bool CAUSAL>
__global__ __launch_bounds__(256, 2)
void diff_flash(const u16* __restrict__ Q, const u16* __restrict__ Kg, const u16* __restrict__ Vt,
                u16* __restrict__ O, const float* __restrict__ lq1, const float* __restrict__ lk1,
                const float* __restrict__ lq2, const float* __restrict__ lk2, int T, int S) {
    __shared__ u16 sK1[2][64 * 64];
    __shared__ u16 sK2[2][64 * 64];
    __shared__ u16 sV[2][64 * 64];
    __shared__ u16 sP[4][16 * 64];

    const int tid = threadIdx.x;
    const int w = tid >> 6, lane = tid & 63, q4 = lane >> 4, l16 = lane & 15;
    const int h = blockIdx.x, b = blockIdx.y;
    const int zt = CAUSAL ? (gridDim.z - 1 - blockIdx.z) : blockIdx.z;  // heavy blocks first
    const int t0 = zt * 64;
    const f32x4 fzero = {0.f, 0.f, 0.f, 0.f};

    float d1 = 0.f, d2 = 0.f;
    for (int d = 0; d < 64; ++d) {
        d1 += lq1[h * 64 + d] * lk1[h * 64 + d];
        d2 += lq2[h * 64 + d] * lk2[h * 64 + d];
    }
    const float lam = __expf(d1) - __expf(d2) + 0.8f;

    // Q fragments (B-operand: lane l16 = t, k = q4*8+j), both comps
    s16x8 qf[2][2];
    {
        const size_t qrow = (size_t)(b * T + t0 + w * 16 + l16) * 2048 + h * 128;
#pragma unroll
        for (int c = 0; c < 2; ++c)
#pragma unroll
            for (int kk = 0; kk < 2; ++kk)
                qf[c][kk] = *(const s16x8*)&Q[qrow + c * 64 + kk * 32 + q4 * 8];
    }

    f32x4 o1[4], o2[4];          // O^T accum: o[jn] rows d=jn*16+q4*4+r, col t=l16
    float ms1 = -1e30f, ls1 = 0.f, ms2 = -1e30f, ls2 = 0.f;
#pragma unroll
    for (int jn = 0; jn < 4; ++jn) { o1[jn] = fzero; o2[jn] = fzero; }

    const int ntiles = CAUSAL ? (zt + 1) : (S / 64);
    const int rk = tid >> 3;                    // staging row 0..31
    const int ckk = (((tid & 7) - rk) & 7) * 8; // rotated source chunk (elems)

    auto stage = [&](int buf, int s0) {
        const size_t kb = (size_t)(b * S + s0 + rk) * 2048 + h * 128;
        gld_lds16(&Kg[kb + ckk], &sK1[buf][tid * 8]);
        gld_lds16(&Kg[kb + (size_t)32 * 2048 + ckk], &sK1[buf][(256 + tid) * 8]);
        gld_lds16(&Kg[kb + 64 + ckk], &sK2[buf][tid * 8]);
        gld_lds16(&Kg[kb + (size_t)32 * 2048 + 64 + ckk], &sK2[buf][(256 + tid) * 8]);
        const size_t vb = (size_t)((b * 16 + h) * 64 + rk) * 1024 + s0;
        gld_lds16(&Vt[vb + ckk], &sV[buf][tid * 8]);
        gld_lds16(&Vt[vb + (size_t)32 * 1024 + ckk], &sV[buf][(256 + tid) * 8]);
    };

    u16* const sPw = sP[w];
    const int slot0 = ((0 * 4 + q4 + l16) & 7) * 8;   // read slot, kk=0
    const int slot1 = ((1 * 4 + q4 + l16) & 7) * 8;   // read slot, kk=1

    stage(0, 0);
    for (int it = 0; it < ntiles; ++it) {
        WAIT_VM0();
        __syncthreads();
        if (it + 1 < ntiles) stage((it + 1) & 1, (it + 1) * 64);
        const int buf = it & 1, s0 = it * 64;
        const bool diag = CAUSAL && (it == ntiles - 1);

        // V fragments (A-operand: lane l16 = d row), shared by both comps
        s16x8 vf[4][2];
#pragma unroll
        for (int jn = 0; jn < 4; ++jn) {
            vf[jn][0] = *(const s16x8*)&sV[buf][(jn * 16 + l16) * 64 + slot0];
            vf[jn][1] = *(const s16x8*)&sV[buf][(jn * 16 + l16) * 64 + slot1];
        }

        auto comp_step = [&](const u16* sK, const s16x8* qkk, float& m, float& l, f32x4* o) {
            f32x4 sc[4];
#pragma unroll
            for (int js = 0; js < 4; ++js) sc[js] = fzero;
#pragma unroll
            for (int js = 0; js < 4; ++js) {
                s16x8 kf0 = *(const s16x8*)&sK[(js * 16 + l16) * 64 + slot0];
                sc[js] = __builtin_amdgcn_mfma_f32_16x16x32_bf16(kf0, qkk[0], sc[js], 0, 0, 0);
                s16x8 kf1 = *(const s16x8*)&sK[(js * 16 + l16) * 64 + slot1];
                sc[js] = __builtin_amdgcn_mfma_f32_16x16x32_bf16(kf1, qkk[1], sc[js], 0, 0, 0);
            }
            float p[4][4];
#pragma unroll
            for (int js = 0; js < 4; ++js)
#pragma unroll
                for (int r = 0; r < 4; ++r) {
                    float v = sc[js][r] * 0.125f;
                    if (diag && (s0 + js * 16 + q4 * 4 + r > t0 + w * 16 + l16)) v = -1e9f;
                    p[js][r] = v;
                }
            float mx = p[0][0];
#pragma unroll
            for (int js = 0; js < 4; ++js)
#pragma unroll
                for (int r = 0; r < 4; ++r) mx = fmaxf(mx, p[js][r]);
            mx = fmaxf(mx, __shfl_xor(mx, 16, 64));
            mx = fmaxf(mx, __shfl_xor(mx, 32, 64));
            float mn = fmaxf(m, mx);
            float alpha = __expf(m - mn);
            m = mn;
            float rs = 0.f;
#pragma unroll
            for (int js = 0; js < 4; ++js)
#pragma unroll
                for (int r = 0; r < 4; ++r) { p[js][r] = __expf(p[js][r] - mn); rs += p[js][r]; }
            rs += __shfl_xor(rs, 16, 64);
            rs += __shfl_xor(rs, 32, 64);
            l = l * alpha + rs;
#pragma unroll
            for (int jn = 0; jn < 4; ++jn) o[jn] *= alpha;
            // P^T -> LDS (rotated): row t=l16, chunk = js*2+(q4>>1), half = q4&1
#pragma unroll
            for (int js = 0; js < 4; ++js) {
                ushort4 pk;
                pk.x = f2bu(p[js][0]); pk.y = f2bu(p[js][1]);
                pk.z = f2bu(p[js][2]); pk.w = f2bu(p[js][3]);
                int sl = ((js * 2 + (q4 >> 1) + l16) & 7) * 8 + (q4 & 1) * 4;
                *(ushort4*)&sPw[l16 * 64 + sl] = pk;
            }
            WAIT_LGKM0();
            s16x8 pb0 = *(const s16x8*)&sPw[l16 * 64 + slot0];
            s16x8 pb1 = *(const s16x8*)&sPw[l16 * 64 + slot1];
#pragma unroll
            for (int jn = 0; jn < 4; ++jn) {
                o[jn] = __builtin_amdgcn_mfma_f32_16x16x32_bf16(vf[jn][0], pb0, o[jn], 0, 0, 0);
                o[jn] = __builtin_amdgcn_mfma_f32_16x16x32_bf16(vf[jn][1], pb1, o[jn], 0, 0, 0);
            }
            MEMBAR();
        };
        comp_step(sK1[buf], qf[0], ms1, ls1, o1);
        comp_step(sK2[buf], qf[1], ms2, ls2, o2);
        __syncthreads();
    }

    // finalize: val = o1/l1 - lam*o2/l2 (per-lane scalars), RMS over d (in-lane + 2 shuffles)
    const float inv1 = 1.f / ls1, inv2 = lam / ls2;
    float val[4][4];
    float ss = 0.f;
#pragma unroll
    for (int jn = 0; jn < 4; ++jn)
#pragma unroll
        for (int r = 0; r < 4; ++r) {
            float v = o1[jn][r] * inv1 - o2[jn][r] * inv2;
            val[jn][r] = v;
            ss += v * v;
        }
    ss += __shfl_xor(ss, 16, 64);
    ss += __shfl_xor(ss, 32, 64);
    const float scl = rsqrtf(ss * (1.f / 64.f) + 1e-6f) * 0.2f;
    const size_t orow = (size_t)(b * T + t0 + w * 16 + l16) * 1024 + h * 64;
#pragma unroll
    for (int jn = 0; jn < 4; ++jn) {
        ushort4 ov;
        ov.x = f2bu(val[jn][0] * scl); ov.y = f2bu(val[jn][1] * scl);
        ov.z = f2bu(val[jn][2] * scl); ov.w = f2bu(val[jn][3] * scl);
        *(ushort4*)&O[orow + jn * 16 + q4 * 4] = ov;
    }
}

// ---------------------------------------------------------------- launch
extern "C" void kernel_launch(void* const* d_in, const int* in_sizes, int n_in,
                              void* d_out, int out_size, void* d_ws, size_t ws_size,
                              hipStream_t stream) {
    (void)in_sizes; (void)n_in; (void)out_size; (void)ws_size;
    const float* x     = (const float*)d_in[0];
    const float* enc   = (const float*)d_in[1];
    const float* Wq_s  = (const float*)d_in[2];
    const float* Wk_s  = (const float*)d_in[3];
    const float* Wv_s  = (const float*)d_in[4];
    const float* Wo_s  = (const float*)d_in[5];
    const float* lq1_s = (const float*)d_in[6];
    const float* lk1_s = (const float*)d_in[7];
    const float* lq2_s = (const float*)d_in[8];
    const float* lk2_s = (const float*)d_in[9];
    const float* Wq_c  = (const float*)d_in[10];
    const float* Wk_c  = (const float*)d_in[11];
    const float* Wv_c  = (const float*)d_in[12];
    const float* Wo_c  = (const float*)d_in[13];
    const float* lq1_c = (const float*)d_in[14];
    const float* lk1_c = (const float*)d_in[15];
    const float* lq2_c = (const float*)d_in[16];
    const float* lk2_c = (const float*)d_in[17];
    const float* g_rms = (const float*)d_in[18];
    const float* W1    = (const float*)d_in[19];
    const float* W2    = (const float*)d_in[20];
    const float* W3    = (const float*)d_in[21];

    char* ws = (char*)d_ws;
    size_t off = 0;
    auto ab = [&](size_t elems) -> u16* { u16* p = (u16*)(ws + off); off += elems * 2; return p; };
    u16* WqkvTs = ab((size_t)5120 * 1024);   // [WqT;WkT;WvT]
    u16* WoTs   = ab((size_t)1024 * 1024);
    u16* WqTc   = ab((size_t)2048 * 1024);
    u16* WkvTc  = ab((size_t)3072 * 1024);   // [WkT;WvT]
    u16* WoTc   = ab((size_t)1024 * 1024);
    u16* W12T   = ab((size_t)8192 * 1024);   // [W1T;W2T]
    u16* W3T    = ab((size_t)1024 * 4096);
    char* pool = ws + off;
    u16* h0   = ab((size_t)4096 * 1024);
    u16* encb = ab((size_t)4096 * 1024);
    u16* Qb   = ab((size_t)4096 * 2048);     // Qb,Kb,Vt contiguous (mode 5/6 routing)
    u16* Kb   = ab((size_t)4096 * 2048);
    u16* Vt   = ab((size_t)4096 * 1024);
    u16* Ob   = ab((size_t)4096 * 1024);
    u16* fa   = (u16*)pool;                              // 32MB = h0+encb+Qb (dead by FFN)
    u16* fb   = (u16*)(pool + (size_t)4096 * 4096 * 2);  // 32MB = Kb+Vt+Ob
    u16* h1   = ab((size_t)4096 * 1024);
    float* h2 = (float*)(ws + off); off += (size_t)4096 * 1024 * 4;
    u16* rn   = ab((size_t)4096 * 1024);

    dim3 tb(32, 8);
    // class R=1024,C=2048: Wq_s, Wk_s, Wq_c, Wk_c
    transpose4_k<<<dim3(64, 32, 4), tb, 0, stream>>>(
        Wq_s, Wk_s, Wq_c, Wk_c,
        WqkvTs, WqkvTs + (size_t)2048 * 1024, WqTc, WkvTc, 1024, 2048);
    // class R=1024,C=1024: Wv_s, Wo_s, Wv_c, Wo_c
    transpose4_k<<<dim3(32, 32, 4), tb, 0, stream>>>(
        Wv_s, Wo_s, Wv_c, Wo_c,
        WqkvTs + (size_t)4096 * 1024, WoTs, WkvTc + (size_t)2048 * 1024, WoTc, 1024, 1024);
    // class R=1024,C=4096: W1, W2
    transpose4_k<<<dim3(128, 32, 2), tb, 0, stream>>>(
        W1, W2, W1, W2, W12T, W12T + (size_t)4096 * 1024, W12T, W12T, 1024, 4096);
    // W3: 4096x1024
    transpose4_k<<<dim3(32, 128, 1), tb, 0, stream>>>(W3, W3, W3, W3, W3T, W3T, W3T, W3T, 4096, 1024);

    rmsnorm_k<<<4096, 256, 0, stream>>>(x, g_rms, h0);
    convert_k<<<4096, 256, 0, stream>>>(enc, encb, 4096 * 1024 / 4);

    // self attention (causal); residual = h0 (normed input, per reference)
    gemm_bt<128><<<dim3(40, 32), 256, 0, stream>>>(h0, WqkvTs, Qb, nullptr, 4096, 5120, 1024, 5);
    diff_flash<true><<<dim3(16, 4, 16), 256, 0, stream>>>(Qb, Kb, Vt, Ob, lq1_s, lk1_s, lq2_s, lk2_s, 1024, 1024);
    gemm_bt<64><<<dim3(8, 64), 256, 0, stream>>>(Ob, WoTs, h1, h0, 4096, 1024, 1024, 1);

    // cross attention (non-causal); then h = h + h (2x folded in epilogue)
    gemm_bt<128><<<dim3(16, 32), 256, 0, stream>>>(h1, WqTc, Qb, nullptr, 4096, 2048, 1024, 0);
    gemm_bt<128><<<dim3(24, 32), 256, 0, stream>>>(encb, WkvTc, Kb, nullptr, 4096, 3072, 1024, 6);
    diff_flash<false><<<dim3(16, 4, 16), 256, 0, stream>>>(Qb, Kb, Vt, Ob, lq1_c, lk1_c, lq2_c, lk2_c, 1024, 1024);
    gemm_bt<64><<<dim3(8, 64), 256, 0, stream>>>(Ob, WoTc, h2, nullptr, 4096, 1024, 1024, 2);

    // FFN: out = (silu(rn@W1) * (rn@W2)) @ W3 + h2
    rmsnorm_k<<<4096, 256, 0, stream>>>(h2, g_rms, rn);
    gemm_bt<128><<<dim3(64, 32), 256, 0, stream>>>(rn, W12T, fa, nullptr, 4096, 8192, 1024, 7);
    silumul_k<<<16384, 256, 0, stream>>>(fa, fb, fa, 4096 * 4096 / 4);
    gemm_bt<64><<<dim3(8, 64), 256, 0, stream>>>(fa, W3T, (float*)d_out, h2, 4096, 1024, 4096, 4);
}

// Round 5
// 754.298 us; speedup vs baseline: 1.3546x; 1.0046x over previous
//
#include <hip/hip_runtime.h>

typedef __attribute__((ext_vector_type(8))) short s16x8;
typedef __attribute__((ext_vector_type(4))) float f32x4;
typedef unsigned short u16;

__device__ __forceinline__ float bu2f(u16 u) {
    union { unsigned int i; float f; } x; x.i = ((unsigned int)u) << 16; return x.f;
}
__device__ __forceinline__ u16 f2bu(float f) {
    union { float f; unsigned int i; } x; x.f = f;
    unsigned int r = x.i + 0x7fffu + ((x.i >> 16) & 1u);   // RNE
    return (u16)(r >> 16);
}

__device__ __forceinline__ void gld_lds16(const void* g, void* l) {
    __builtin_amdgcn_global_load_lds(
        (const __attribute__((address_space(1))) unsigned int*)g,
        (__attribute__((address_space(3))) unsigned int*)l, 16, 0, 0);
}
#define WAIT_VM0()   asm volatile("s_waitcnt vmcnt(0)" ::: "memory")
#define WAIT_LGKM0() asm volatile("s_waitcnt lgkmcnt(0)" ::: "memory")
#define RAW_BARRIER() asm volatile("s_barrier" ::: "memory")
#define MEMBAR()     asm volatile("" ::: "memory")

// ---------------------------------------------------------------- batched transpose + f32->bf16
__global__ __launch_bounds__(256)
void transpose4_k(const float* s0, const float* s1, const float* s2, const float* s3,
                  u16* d0, u16* d1, u16* d2, u16* d3, int R, int C) {
    const float* src = blockIdx.z == 0 ? s0 : blockIdx.z == 1 ? s1 : blockIdx.z == 2 ? s2 : s3;
    u16* dst = blockIdx.z == 0 ? d0 : blockIdx.z == 1 ? d1 : blockIdx.z == 2 ? d2 : d3;
    __shared__ u16 t[32][33];
    int bx = blockIdx.x * 32, by = blockIdx.y * 32;
    int x = bx + threadIdx.x;
#pragma unroll
    for (int k = 0; k < 4; ++k)
        t[threadIdx.y + k * 8][threadIdx.x] = f2bu(src[(size_t)(by + threadIdx.y + k * 8) * C + x]);
    __syncthreads();
    int x2 = by + threadIdx.x;
#pragma unroll
    for (int k = 0; k < 4; ++k)
        dst[(size_t)(bx + threadIdx.y + k * 8) * R + x2] = t[threadIdx.x][threadIdx.y + k * 8];
}

// ---------------------------------------------------------------- f32 -> bf16 convert
__global__ __launch_bounds__(256)
void convert_k(const float* __restrict__ a, u16* __restrict__ o, int n4) {
    int i = blockIdx.x * 256 + threadIdx.x;
    if (i >= n4) return;
    float4 v = ((const float4*)a)[i];
    ushort4 u;
    u.x = f2bu(v.x); u.y = f2bu(v.y); u.z = f2bu(v.z); u.w = f2bu(v.w);
    ((ushort4*)o)[i] = u;
}

// ---------------------------------------------------------------- rmsnorm (row = 1024), f32 in -> bf16 out
__global__ __launch_bounds__(256)
void rmsnorm_k(const float* __restrict__ x, const float* __restrict__ g, u16* __restrict__ y) {
    const int row = blockIdx.x, tid = threadIdx.x;
    float4 v = ((const float4*)(x + (size_t)row * 1024))[tid];
    float ss = v.x * v.x + v.y * v.y + v.z * v.z + v.w * v.w;
#pragma unroll
    for (int off = 32; off; off >>= 1) ss += __shfl_xor(ss, off, 64);
    __shared__ float red[4];
    if ((tid & 63) == 0) red[tid >> 6] = ss;
    __syncthreads();
    float tot = red[0] + red[1] + red[2] + red[3];
    float sc = rsqrtf(tot * (1.f / 1024.f) + 1e-6f);
    float4 gv = ((const float4*)g)[tid];
    ushort4 o;
    o.x = f2bu(v.x * sc * gv.x);
    o.y = f2bu(v.y * sc * gv.y);
    o.z = f2bu(v.z * sc * gv.z);
    o.w = f2bu(v.w * sc * gv.w);
    ((ushort4*)(y + (size_t)row * 1024))[tid] = o;
}

// ---------------------------------------------------------------- silu(a)*b  (bf16)
__global__ __launch_bounds__(256)
void silumul_k(const u16* __restrict__ a, const u16* __restrict__ b, u16* __restrict__ o, int n4) {
    int i = blockIdx.x * 256 + threadIdx.x;
    if (i >= n4) return;
    ushort4 ua = ((const ushort4*)a)[i], ub = ((const ushort4*)b)[i];
    ushort4 uo;
    {
        float v = bu2f(ua.x); uo.x = f2bu(v / (1.f + __expf(-v)) * bu2f(ub.x));
        v = bu2f(ua.y); uo.y = f2bu(v / (1.f + __expf(-v)) * bu2f(ub.y));
        v = bu2f(ua.z); uo.z = f2bu(v / (1.f + __expf(-v)) * bu2f(ub.z));
        v = bu2f(ua.w); uo.w = f2bu(v / (1.f + __expf(-v)) * bu2f(ub.w));
    }
    ((ushort4*)o)[i] = uo;
}

// ---------------------------------------------------------------- GEMM  C(M,N) = A(M,K) @ Bt(N,K)^T
// Double-buffered K-loop with raw s_barrier (prefetch stays in flight across the
// barrier; one barrier per K-iter). modes as before.
template <int TM>
__global__ __launch_bounds__(256, 2)
void gemm_bt(const u16* __restrict__ A, const u16* __restrict__ Bt, void* __restrict__ C,
             const void* __restrict__ res, int M, int N, int K, int mode) {
    constexpr int MI = TM / 32;
    __shared__ u16 sA[2][TM * 32];
    __shared__ u16 sB[2][128 * 32];
    const int tid = threadIdx.x;
    const int w = tid >> 6, lane = tid & 63, q4 = lane >> 4, l16 = lane & 15;
    const int m0 = blockIdx.y * TM, n0 = blockIdx.x * 128;
    const int wm = (w >> 1) * (TM / 2), wn = (w & 1) * 64;

    const f32x4 fzero = {0.f, 0.f, 0.f, 0.f};
    f32x4 acc[MI][4];
#pragma unroll
    for (int i = 0; i < MI; ++i)
#pragma unroll
        for (int j = 0; j < 4; ++j) acc[i][j] = fzero;

    const int r0 = tid >> 2, c0 = (tid & 3) * 8;

    auto stage = [&](int buf, int k0) {
        gld_lds16(A + (size_t)(m0 + r0) * K + k0 + c0, &sA[buf][tid * 8]);
        if (TM == 128)
            gld_lds16(A + (size_t)(m0 + 64 + r0) * K + k0 + c0, &sA[buf][(256 + tid) * 8]);
        gld_lds16(Bt + (size_t)(n0 + r0) * K + k0 + c0, &sB[buf][tid * 8]);
        gld_lds16(Bt + (size_t)(n0 + 64 + r0) * K + k0 + c0, &sB[buf][(256 + tid) * 8]);
    };

    const int nk = K >> 5;
    stage(0, 0);
    for (int it = 0; it < nk; ++it) {
        WAIT_VM0();        // my stage(it) loads done (all waves do this)
        RAW_BARRIER();     // everyone's stage(it) done; buf^1 free to overwrite
        if (it + 1 < nk) stage((it + 1) & 1, (it + 1) * 32);
        const int buf = it & 1;
        s16x8 af[MI], bfr[4];
#pragma unroll
        for (int i = 0; i < MI; ++i) af[i] = *(const s16x8*)&sA[buf][(wm + i * 16 + l16) * 32 + q4 * 8];
#pragma unroll
        for (int j = 0; j < 4; ++j) bfr[j] = *(const s16x8*)&sB[buf][(wn + j * 16 + l16) * 32 + q4 * 8];
#pragma unroll
        for (int i = 0; i < MI; ++i)
#pragma unroll
            for (int j = 0; j < 4; ++j)
                acc[i][j] = __builtin_amdgcn_mfma_f32_16x16x32_bf16(af[i], bfr[j], acc[i][j], 0, 0, 0);
        MEMBAR();
    }

    const size_t QBSZ = (size_t)4096 * 2048;
    const size_t FSZ  = (size_t)4096 * 4096;
#pragma unroll
    for (int i = 0; i < MI; ++i)
#pragma unroll
        for (int j = 0; j < 4; ++j)
#pragma unroll
            for (int r = 0; r < 4; ++r) {
                int m = m0 + wm + i * 16 + q4 * 4 + r;
                int n = n0 + wn + j * 16 + l16;
                float v = acc[i][j][r];
                if (mode == 0) {
                    ((u16*)C)[(size_t)m * N + n] = f2bu(v);
                } else if (mode == 1) {
                    ((u16*)C)[(size_t)m * N + n] = f2bu(v + bu2f(((const u16*)res)[(size_t)m * N + n]));
                } else if (mode == 2) {
                    ((float*)C)[(size_t)m * N + n] = 2.f * v;
                } else if (mode == 4) {
                    ((float*)C)[(size_t)m * N + n] = v + ((const float*)res)[(size_t)m * N + n];
                } else if (mode == 5) {
                    if (n < 2048) ((u16*)C)[(size_t)m * 2048 + n] = f2bu(v);
                    else if (n < 4096) ((u16*)C)[QBSZ + (size_t)m * 2048 + (n - 2048)] = f2bu(v);
                    else {
                        int nn = n - 4096, hh = nn >> 6, d = nn & 63, b = m >> 10, s = m & 1023;
                        ((u16*)C)[2 * QBSZ + ((size_t)((b * 16 + hh) * 64 + d)) * 1024 + s] = f2bu(v);
                    }
                } else if (mode == 6) {
                    if (n < 2048) ((u16*)C)[(size_t)m * 2048 + n] = f2bu(v);
                    else {
                        int nn = n - 2048, hh = nn >> 6, d = nn & 63, b = m >> 10, s = m & 1023;
                        ((u16*)C)[QBSZ + ((size_t)((b * 16 + hh) * 64 + d)) * 1024 + s] = f2bu(v);
                    }
                } else {  // 7
                    if (n < 4096) ((u16*)C)[(size_t)m * 4096 + n] = f2bu(v);
                    else ((u16*)C)[FSZ + (size_t)m * 4096 + (n - 4096)] = f2bu(v);
                }
            }
}

// ---------------------------------------------------------------- fused differential flash attention v4
// v3 + raw-barrier loop (1 barrier per tile, prefetch in flight across it).
template <bool CAUSAL>
__global__ __launch_bounds__(256, 2)
void diff_flash(const u16* __restrict__ Q, const u16* __restrict__ Kg, const u16* __restrict__ Vt,
                u16* __restrict__ O, const float* __restrict__ lq1, const float* __restrict__ lk1,
                const float* __restrict__ lq2, const float* __restrict__ lk2, int T, int S) {
    __shared__ u16 sK1[2][64 * 64];
    __shared__ u16 sK2[2][64 * 64];
    __shared__ u16 sV[2][64 * 64];
    __shared__ u16 sP[4][16 * 64];

    const int tid = threadIdx.x;
    const int w = tid >> 6, lane = tid & 63, q4 = lane >> 4, l16 = lane & 15;
    const int h = blockIdx.x, b = blockIdx.y;
    const int zt = CAUSAL ? (gridDim.z - 1 - blockIdx.z) : blockIdx.z;  // heavy blocks first
    const int t0 = zt * 64;
    const f32x4 fzero = {0.f, 0.f, 0.f, 0.f};

    float d1 = 0.f, d2 = 0.f;
    for (int d = 0; d < 64; ++d) {
        d1 += lq1[h * 64 + d] * lk1[h * 64 + d];
        d2 += lq2[h * 64 + d] * lk2[h * 64 + d];
    }
    const float lam = __expf(d1) - __expf(d2) + 0.8f;

    // Q fragments (B-operand: lane l16 = t, k = q4*8+j), both comps
    s16x8 qf[2][2];
    {
        const size_t qrow = (size_t)(b * T + t0 + w * 16 + l16) * 2048 + h * 128;
#pragma unroll
        for (int c = 0; c < 2; ++c)
#pragma unroll
            for (int kk = 0; kk < 2; ++kk)
                qf[c][kk] = *(const s16x8*)&Q[qrow + c * 64 + kk * 32 + q4 * 8];
    }

    f32x4 o1[4], o2[4];          // O^T accum: o[jn] rows d=jn*16+q4*4+r, col t=l16
    float ms1 = -1e30f, ls1 = 0.f, ms2 = -1e30f, ls2 = 0.f;
#pragma unroll
    for (int jn = 0; jn < 4; ++jn) { o1[jn] = fzero; o2[jn] = fzero; }

    const int ntiles = CAUSAL ? (zt + 1) : (S / 64);
    const int rk = tid >> 3;                    // staging row 0..31
    const int ckk = (((tid & 7) - rk) & 7) * 8; // rotated source chunk (elems)

    auto stage = [&](int buf, int s0) {
        const size_t kb = (size_t)(b * S + s0 + rk) * 2048 + h * 128;
        gld_lds16(&Kg[kb + ckk], &sK1[buf][tid * 8]);
        gld_lds16(&Kg[kb + (size_t)32 * 2048 + ckk], &sK1[buf][(256 + tid) * 8]);
        gld_lds16(&Kg[kb + 64 + ckk], &sK2[buf][tid * 8]);
        gld_lds16(&Kg[kb + (size_t)32 * 2048 + 64 + ckk], &sK2[buf][(256 + tid) * 8]);
        const size_t vb = (size_t)((b * 16 + h) * 64 + rk) * 1024 + s0;
        gld_lds16(&Vt[vb + ckk], &sV[buf][tid * 8]);
        gld_lds16(&Vt[vb + (size_t)32 * 1024 + ckk], &sV[buf][(256 + tid) * 8]);
    };

    u16* const sPw = sP[w];
    const int slot0 = ((0 * 4 + q4 + l16) & 7) * 8;   // read slot, kk=0
    const int slot1 = ((1 * 4 + q4 + l16) & 7) * 8;   // read slot, kk=1

    stage(0, 0);
    for (int it = 0; it < ntiles; ++it) {
        WAIT_VM0();
        RAW_BARRIER();
        if (it + 1 < ntiles) stage((it + 1) & 1, (it + 1) * 64);
        const int buf = it & 1, s0 = it * 64;
        const bool diag = CAUSAL && (it == ntiles - 1);

        // V fragments (A-operand: lane l16 = d row), shared by both comps
        s16x8 vf[4][2];
#pragma unroll
        for (int jn = 0; jn < 4; ++jn) {
            vf[jn][0] = *(const s16x8*)&sV[buf][(jn * 16 + l16) * 64 + slot0];
            vf[jn][1] = *(const s16x8*)&sV[buf][(jn * 16 + l16) * 64 + slot1];
        }

        auto comp_step = [&](const u16* sK, const s16x8* qkk, float& m, float& l, f32x4* o) {
            f32x4 sc[4];
#pragma unroll
            for (int js = 0; js < 4; ++js) sc[js] = fzero;
#pragma unroll
            for (int js = 0; js < 4; ++js) {
                s16x8 kf0 = *(const s16x8*)&sK[(js * 16 + l16) * 64 + slot0];
                sc[js] = __builtin_amdgcn_mfma_f32_16x16x32_bf16(kf0, qkk[0], sc[js], 0, 0, 0);
                s16x8 kf1 = *(const s16x8*)&sK[(js * 16 + l16) * 64 + slot1];
                sc[js] = __builtin_amdgcn_mfma_f32_16x16x32_bf16(kf1, qkk[1], sc[js], 0, 0, 0);
            }
            float p[4][4];
#pragma unroll
            for (int js = 0; js < 4; ++js)
#pragma unroll
                for (int r = 0; r < 4; ++r) {
                    float v = sc[js][r] * 0.125f;
                    if (diag && (s0 + js * 16 + q4 * 4 + r > t0 + w * 16 + l16)) v = -1e9f;
                    p[js][r] = v;
                }
            float mx = p[0][0];
#pragma unroll
            for (int js = 0; js < 4; ++js)
#pragma unroll
                for (int r = 0; r < 4; ++r) mx = fmaxf(mx, p[js][r]);
            mx = fmaxf(mx, __shfl_xor(mx, 16, 64));
            mx = fmaxf(mx, __shfl_xor(mx, 32, 64));
            float mn = fmaxf(m, mx);
            float alpha = __expf(m - mn);
            m = mn;
            float rs = 0.f;
#pragma unroll
            for (int js = 0; js < 4; ++js)
#pragma unroll
                for (int r = 0; r < 4; ++r) { p[js][r] = __expf(p[js][r] - mn); rs += p[js][r]; }
            rs += __shfl_xor(rs, 16, 64);
            rs += __shfl_xor(rs, 32, 64);
            l = l * alpha + rs;
#pragma unroll
            for (int jn = 0; jn < 4; ++jn) o[jn] *= alpha;
            // P^T -> LDS (rotated): row t=l16, chunk = js*2+(q4>>1), half = q4&1
#pragma unroll
            for (int js = 0; js < 4; ++js) {
                ushort4 pk;
                pk.x = f2bu(p[js][0]); pk.y = f2bu(p[js][1]);
                pk.z = f2bu(p[js][2]); pk.w = f2bu(p[js][3]);
                int sl = ((js * 2 + (q4 >> 1) + l16) & 7) * 8 + (q4 & 1) * 4;
                *(ushort4*)&sPw[l16 * 64 + sl] = pk;
            }
            WAIT_LGKM0();
            s16x8 pb0 = *(const s16x8*)&sPw[l16 * 64 + slot0];
            s16x8 pb1 = *(const s16x8*)&sPw[l16 * 64 + slot1];
#pragma unroll
            for (int jn = 0; jn < 4; ++jn) {
                o[jn] = __builtin_amdgcn_mfma_f32_16x16x32_bf16(vf[jn][0], pb0, o[jn], 0, 0, 0);
                o[jn] = __builtin_amdgcn_mfma_f32_16x16x32_bf16(vf[jn][1], pb1, o[jn], 0, 0, 0);
            }
            MEMBAR();
        };
        comp_step(sK1[buf], qf[0], ms1, ls1, o1);
        comp_step(sK2[buf], qf[1], ms2, ls2, o2);
    }

    // finalize: val = o1/l1 - lam*o2/l2 (per-lane scalars), RMS over d (in-lane + 2 shuffles)
    const float inv1 = 1.f / ls1, inv2 = lam / ls2;
    float val[4][4];
    float ss = 0.f;
#pragma unroll
    for (int jn = 0; jn < 4; ++jn)
#pragma unroll
        for (int r = 0; r < 4; ++r) {
            float v = o1[jn][r] * inv1 - o2[jn][r] * inv2;
            val[jn][r] = v;
            ss += v * v;
        }
    ss += __shfl_xor(ss, 16, 64);
    ss += __shfl_xor(ss, 32, 64);
    const float scl = rsqrtf(ss * (1.f / 64.f) + 1e-6f) * 0.2f;
    const size_t orow = (size_t)(b * T + t0 + w * 16 + l16) * 1024 + h * 64;
#pragma unroll
    for (int jn = 0; jn < 4; ++jn) {
        ushort4 ov;
        ov.x = f2bu(val[jn][0] * scl); ov.y = f2bu(val[jn][1] * scl);
        ov.z = f2bu(val[jn][2] * scl); ov.w = f2bu(val[jn][3] * scl);
        *(ushort4*)&O[orow + jn * 16 + q4 * 4] = ov;
    }
}

// ---------------------------------------------------------------- launch
extern "C" void kernel_launch(void* const* d_in, const int* in_sizes, int n_in,
                              void* d_out, int out_size, void* d_ws, size_t ws_size,
                              hipStream_t stream) {
    (void)in_sizes; (void)n_in; (void)out_size; (void)ws_size;
    const float* x     = (const float*)d_in[0];
    const float* enc   = (const float*)d_in[1];
    const float* Wq_s  = (const float*)d_in[2];
    const float* Wk_s  = (const float*)d_in[3];
    const float* Wv_s  = (const float*)d_in[4];
    const float* Wo_s  = (const float*)d_in[5];
    const float* lq1_s = (const float*)d_in[6];
    const float* lk1_s = (const float*)d_in[7];
    const float* lq2_s = (const float*)d_in[8];
    const float* lk2_s = (const float*)d_in[9];
    const float* Wq_c  = (const float*)d_in[10];
    const float* Wk_c  = (const float*)d_in[11];
    const float* Wv_c  = (const float*)d_in[12];
    const float* Wo_c  = (const float*)d_in[13];
    const float* lq1_c = (const float*)d_in[14];
    const float* lk1_c = (const float*)d_in[15];
    const float* lq2_c = (const float*)d_in[16];
    const float* lk2_c = (const float*)d_in[17];
    const float* g_rms = (const float*)d_in[18];
    const float* W1    = (const float*)d_in[19];
    const float* W2    = (const float*)d_in[20];
    const float* W3    = (const float*)d_in[21];

    char* ws = (char*)d_ws;
    size_t off = 0;
    auto ab = [&](size_t elems) -> u16* { u16* p = (u16*)(ws + off); off += elems * 2; return p; };
    u16* WqkvTs = ab((size_t)5120 * 1024);   // [WqT;WkT;WvT]
    u16* WoTs   = ab((size_t)1024 * 1024);
    u16* WqTc   = ab((size_t)2048 * 1024);
    u16* WkvTc  = ab((size_t)3072 * 1024);   // [WkT;WvT]
    u16* WoTc   = ab((size_t)1024 * 1024);
    u16* W12T   = ab((size_t)8192 * 1024);   // [W1T;W2T]
    u16* W3T    = ab((size_t)1024 * 4096);
    char* pool = ws + off;
    u16* h0   = ab((size_t)4096 * 1024);
    u16* encb = ab((size_t)4096 * 1024);
    u16* Qb   = ab((size_t)4096 * 2048);     // Qb,Kb,Vt contiguous (mode 5/6 routing)
    u16* Kb   = ab((size_t)4096 * 2048);
    u16* Vt   = ab((size_t)4096 * 1024);
    u16* Ob   = ab((size_t)4096 * 1024);
    u16* fa   = (u16*)pool;                              // 32MB = h0+encb+Qb (dead by FFN)
    u16* fb   = (u16*)(pool + (size_t)4096 * 4096 * 2);  // 32MB = Kb+Vt+Ob
    u16* h1   = ab((size_t)4096 * 1024);
    float* h2 = (float*)(ws + off); off += (size_t)4096 * 1024 * 4;
    u16* rn   = ab((size_t)4096 * 1024);

    dim3 tb(32, 8);
    transpose4_k<<<dim3(64, 32, 4), tb, 0, stream>>>(
        Wq_s, Wk_s, Wq_c, Wk_c,
        WqkvTs, WqkvTs + (size_t)2048 * 1024, WqTc, WkvTc, 1024, 2048);
    transpose4_k<<<dim3(32, 32, 4), tb, 0, stream>>>(
        Wv_s, Wo_s, Wv_c, Wo_c,
        WqkvTs + (size_t)4096 * 1024, WoTs, WkvTc + (size_t)2048 * 1024, WoTc, 1024, 1024);
    transpose4_k<<<dim3(128, 32, 2), tb, 0, stream>>>(
        W1, W2, W1, W2, W12T, W12T + (size_t)4096 * 1024, W12T, W12T, 1024, 4096);
    transpose4_k<<<dim3(32, 128, 1), tb, 0, stream>>>(W3, W3, W3, W3, W3T, W3T, W3T, W3T, 4096, 1024);

    rmsnorm_k<<<4096, 256, 0, stream>>>(x, g_rms, h0);
    convert_k<<<4096, 256, 0, stream>>>(enc, encb, 4096 * 1024 / 4);

    // self attention (causal); residual = h0 (normed input, per reference)
    gemm_bt<128><<<dim3(40, 32), 256, 0, stream>>>(h0, WqkvTs, Qb, nullptr, 4096, 5120, 1024, 5);
    diff_flash<true><<<dim3(16, 4, 16), 256, 0, stream>>>(Qb, Kb, Vt, Ob, lq1_s, lk1_s, lq2_s, lk2_s, 1024, 1024);
    gemm_bt<64><<<dim3(8, 64), 256, 0, stream>>>(Ob, WoTs, h1, h0, 4096, 1024, 1024, 1);

    // cross attention (non-causal); then h = h + h (2x folded in epilogue)
    gemm_bt<128><<<dim3(16, 32), 256, 0, stream>>>(h1, WqTc, Qb, nullptr, 4096, 2048, 1024, 0);
    gemm_bt<128><<<dim3(24, 32), 256, 0, stream>>>(encb, WkvTc, Kb, nullptr, 4096, 3072, 1024, 6);
    diff_flash<false><<<dim3(16, 4, 16), 256, 0, stream>>>(Qb, Kb, Vt, Ob, lq1_c, lk1_c, lq2_c, lk2_c, 1024, 1024);
    gemm_bt<64><<<dim3(8, 64), 256, 0, stream>>>(Ob, WoTc, h2, nullptr, 4096, 1024, 1024, 2);

    // FFN: out = (silu(rn@W1) * (rn@W2)) @ W3 + h2
    rmsnorm_k<<<4096, 256, 0, stream>>>(h2, g_rms, rn);
    gemm_bt<128><<<dim3(64, 32), 256, 0, stream>>>(rn, W12T, fa, nullptr, 4096, 8192, 1024, 7);
    silumul_k<<<16384, 256, 0, stream>>>(fa, fb, fa, 4096 * 4096 / 4);
    gemm_bt<64><<<dim3(8, 64), 256, 0, stream>>>(fa, W3T, (float*)d_out, h2, 4096, 1024, 4096, 4);
}